// Round 7
// baseline (565.722 us; speedup 1.0000x reference)
//
#include <hip/hip_runtime.h>
#include <math.h>
#include <stdint.h>

// ---------------------------------------------------------------------------
// MultiHeadAttention, softmax over HEAD axis (dim=1), bf16 MFMA pipeline.
// B=4, S=2048, DIM=1024, H=8, DH=128.
//   qp = (Q WQ^T)*1/sqrt(128), kp = K WK^T   [b,s,1024] bf16
//   vt = (V WV^T)^T  [b,h,dh,s] bf16         (casts fused into GEMM staging)
//   fused_attn v10: v9 + DEEP register prefetch (the MLP fix):
//     - all 32 kf loads batch-issued before the QK consume loop (128 VGPR)
//     - all 32 vf loads batch-issued right after QK (kf regs dead -> reuse),
//       in flight across both barriers, consumed register-resident in PV
//     - __launch_bounds__(512,1): 256-VGPR cap so nothing spills (peak ~250)
//     512 blocks (64 qt x 4 b x 2 k-halves), 8 waves = 8 heads, q-tile 32,
//     KT=128, 8 iters. LDS 64 KB (Pl only), merged reduce+normalize in LDS.
//     ctx f32 partials (per k-half), summed in the WO GEMM's A-staging.
// ---------------------------------------------------------------------------

typedef __attribute__((ext_vector_type(8))) __bf16 bf16x8;
typedef __attribute__((ext_vector_type(4))) __bf16 bf16x4;
typedef __attribute__((ext_vector_type(4))) float  f32x4;
typedef __attribute__((ext_vector_type(2))) unsigned int u32x2;

__device__ __forceinline__ f32x4 mfma16(bf16x8 a, bf16x8 b, f32x4 c) {
    return __builtin_amdgcn_mfma_f32_16x16x32_bf16(a, b, c, 0, 0, 0);
}

// async global->LDS, 16B per lane; LDS dest must be wave-uniform-base + lane*16
__device__ __forceinline__ void cp16(void* lds, const void* g) {
    __builtin_amdgcn_global_load_lds(
        (__attribute__((address_space(1))) void*)(void*)(const_cast<void*>(g)),
        (__attribute__((address_space(3))) void*)lds,
        16, 0, 0);
}

// fast exp/rcp: single HW transcendental (CDNA interlocks handle latency).
__device__ __forceinline__ float fexp(float x) {
    float r;
    asm("v_exp_f32 %0, %1" : "=v"(r) : "v"(x * 1.44269504088896341f));
    return r;
}
__device__ __forceinline__ float frcp(float x) {
    float r;
    asm("v_rcp_f32 %0, %1" : "=v"(r) : "v"(x));
    return r;
}

// pack two f32 into a dword of two bf16 (RNE via HW cvt)
__device__ __forceinline__ uint32_t pk2(float a, float b) {
    __bf16 x = (__bf16)a, y = (__bf16)b;
    unsigned short xa = __builtin_bit_cast(unsigned short, x);
    unsigned short yb = __builtin_bit_cast(unsigned short, y);
    return (uint32_t)xa | ((uint32_t)yb << 16);
}
__device__ __forceinline__ float bflo(uint32_t d) {
    return __builtin_bit_cast(float, d << 16);
}
__device__ __forceinline__ float bfhi(uint32_t d) {
    return __builtin_bit_cast(float, d & 0xffff0000u);
}

// ---------------------------------------------------------------------------
// 4 weight tensors in one launch (bf16 for GEMM B-operands)
__global__ void cast4_f32_to_bf16(const float* __restrict__ s0, __bf16* __restrict__ d0,
                                  const float* __restrict__ s1, __bf16* __restrict__ d1,
                                  const float* __restrict__ s2, __bf16* __restrict__ d2,
                                  const float* __restrict__ s3, __bf16* __restrict__ d3,
                                  int n4) {
    const float* s = (blockIdx.y == 0) ? s0 : (blockIdx.y == 1) ? s1
                    : (blockIdx.y == 2) ? s2 : s3;
    __bf16* d = (blockIdx.y == 0) ? d0 : (blockIdx.y == 1) ? d1
               : (blockIdx.y == 2) ? d2 : d3;
    int i = blockIdx.x * blockDim.x + threadIdx.x;
    const int stride = gridDim.x * blockDim.x;
    for (; i < n4; i += stride) {
        float4 f = ((const float4*)s)[i];
        bf16x4 o;
        o[0] = (__bf16)f.x; o[1] = (__bf16)f.y; o[2] = (__bf16)f.z; o[3] = (__bf16)f.w;
        ((bf16x4*)d)[i] = o;
    }
}

// ---------------------------------------------------------------------------
// Batched Q/K/V projection with FUSED f32->bf16 cast in the A-staging.
// grid.z: 0 -> qp=(Q WQ^T)*qscale, 1 -> kp=K WK^T, 2 -> vt=(V WV^T)^T.
// XCD remap: the 8 col-blocks of a row panel share bid%8 -> one XCD.
__global__ __launch_bounds__(256, 2) void qkv_proj(
    const float* __restrict__ Qf, const float* __restrict__ Kf,
    const float* __restrict__ Vf,
    const __bf16* __restrict__ wq, const __bf16* __restrict__ wk,
    const __bf16* __restrict__ wv,
    __bf16* __restrict__ qp, __bf16* __restrict__ kp, __bf16* __restrict__ vtb,
    float qscale)
{
    __shared__ __bf16 As[128 * 32];
    __shared__ __bf16 Bs[128 * 32];
    const int z = blockIdx.z;
    const float*  Af = (z == 0) ? Qf : (z == 1) ? Kf : Vf;
    const __bf16* Bt = (z == 0) ? wq : (z == 1) ? wk : wv;
    __bf16* out      = (z == 0) ? qp : (z == 1) ? kp : vtb;
    const float scale = (z == 0) ? qscale : 1.0f;

    const int tid  = threadIdx.x;
    const int lane = tid & 63;
    const int u = lane >> 4, v = lane & 15;
    const int w = tid >> 6;
    const int wm = (w >> 1) * 64, wn = (w & 1) * 64;
    const int bid = blockIdx.y * 8 + blockIdx.x;
    const long tM = (long)(bid & 63) * 128;
    const int  tN = (bid >> 6) * 128;

    f32x4 acc[4][4];
#pragma unroll
    for (int i = 0; i < 4; ++i)
#pragma unroll
        for (int j = 0; j < 4; ++j) acc[i][j] = (f32x4){0.f, 0.f, 0.f, 0.f};

    const int ar0 = tid >> 2, ak0 = (tid & 3) * 8;
    const int ar1 = ar0 + 64;

    const float*  Ab = Af + tM * 1024;
    const __bf16* Bb = Bt + (long)tN * 1024;

    for (int k0 = 0; k0 < 1024; k0 += 32) {
        __syncthreads();
        // A: reg-staged f32 -> bf16 (fused cast)
        {
            const float* p = Ab + (long)ar0 * 1024 + k0 + ak0;
            float4 x0 = *(const float4*)p, x1 = *(const float4*)(p + 4);
            bf16x8 o;
            o[0] = (__bf16)x0.x; o[1] = (__bf16)x0.y; o[2] = (__bf16)x0.z; o[3] = (__bf16)x0.w;
            o[4] = (__bf16)x1.x; o[5] = (__bf16)x1.y; o[6] = (__bf16)x1.z; o[7] = (__bf16)x1.w;
            *(bf16x8*)&As[ar0 * 32 + ak0] = o;
            const float* q = Ab + (long)ar1 * 1024 + k0 + ak0;
            float4 y0 = *(const float4*)q, y1 = *(const float4*)(q + 4);
            bf16x8 o2;
            o2[0] = (__bf16)y0.x; o2[1] = (__bf16)y0.y; o2[2] = (__bf16)y0.z; o2[3] = (__bf16)y0.w;
            o2[4] = (__bf16)y1.x; o2[5] = (__bf16)y1.y; o2[6] = (__bf16)y1.z; o2[7] = (__bf16)y1.w;
            *(bf16x8*)&As[ar1 * 32 + ak0] = o2;
        }
        // B: async direct to LDS (bf16 weights)
        cp16(&Bs[ar0 * 32 + ak0], Bb + (long)ar0 * 1024 + k0 + ak0);
        cp16(&Bs[ar1 * 32 + ak0], Bb + (long)ar1 * 1024 + k0 + ak0);
        __syncthreads();

        bf16x8 af[4], bfr[4];
#pragma unroll
        for (int i = 0; i < 4; ++i)
            af[i] = *(const bf16x8*)&As[(wm + i * 16 + v) * 32 + u * 8];
#pragma unroll
        for (int j = 0; j < 4; ++j)
            bfr[j] = *(const bf16x8*)&Bs[(wn + j * 16 + v) * 32 + u * 8];
#pragma unroll
        for (int i = 0; i < 4; ++i)
#pragma unroll
            for (int j = 0; j < 4; ++j)
                acc[i][j] = mfma16(af[i], bfr[j], acc[i][j]);
    }

#pragma unroll
    for (int i = 0; i < 4; ++i) {
#pragma unroll
        for (int j = 0; j < 4; ++j) {
            const long row0 = tM + wm + i * 16 + u * 4;
            const int  col  = tN + wn + j * 16 + v;
            if (z < 2) {
#pragma unroll
                for (int r = 0; r < 4; ++r)
                    out[(row0 + r) * 1024 + col] = (__bf16)(acc[i][j][r] * scale);
            } else {
                const int bidx = (int)(row0 >> 11);
                const int s    = (int)(row0 & 2047);          // 4-aligned
                const int h = col >> 7, dh = col & 127;
                bf16x4 pkv;
#pragma unroll
                for (int r = 0; r < 4; ++r) pkv[r] = (__bf16)acc[i][j][r];
                *(bf16x4*)&out[((long)(bidx * 8 + h) * 128 + dh) * 2048 + s] = pkv;
            }
        }
    }
}

// ---------------------------------------------------------------------------
// fused_attn v10: QK^T -> head-softmax -> PV with deep register prefetch.
// 512 blocks: bid = qt*8 + b*2 + kh  (XCD = b*2+kh: K/V halves L2-resident).
// 512 threads = 8 waves, wave w == head. q-tile 32, KT=128, 8 iters.
//
// Pl element (k = ki*16 + kk8*8 + kk4*4 + r, q = qj*16 + vq) of wave slice w
// lives at byte: w*8192 + (qj*16+vq)*256 + ((ki*2+kk8)^(vq&7))*16 + kk4*8 + r*2.
//   step0: ALL 32 kf loads batch-issued (128 VGPR in flight -> one L2
//          latency for the whole tile instead of eight).
//   step1: per ki: 8 QK MFMA (in-order kf consume) + fast exp + pack -> Pl.
//   stepV: ALL 32 vf loads batch-issued (kf dead -> regs reused); they fly
//          across both barriers and the reduce.
//   bar; step2: wave w reduces groups {w, w+8} across all 8 slices AND
//          writes back NORMALIZED values; bar.
//   step3: PV 64 MFMA from register-resident vf + Pl reads.
// LDS: Pl 64 KB. launch_bounds (512,1): 256-VGPR cap, peak ~250, no spill.
__global__ __launch_bounds__(512, 1) void fused_attn(
    const __bf16* __restrict__ qp, const __bf16* __restrict__ kp,
    const __bf16* __restrict__ vt, float* __restrict__ ctxp)
{
    __shared__ __bf16 Pl[8][32][128];   // 64 KB; per-wave slice 8 KB

    const int tid  = threadIdx.x;
    const int w    = tid >> 6;          // wave == head
    const int lane = tid & 63;
    const int u = lane >> 4, v = lane & 15;

    const int bid = blockIdx.x;
    const int kh  = bid & 1;            // k-half
    const int b   = (bid >> 1) & 3;
    const int qt  = bid >> 3;
    const int q0  = qt * 32;
    const int h   = w;

    const __bf16* Qb = qp + ((long)b * 2048 + q0) * 1024 + h * 128;
    const __bf16* Kb = kp + (long)b * 2048 * 1024 + h * 128;
    const __bf16* Vb = vt + (long)(b * 8 + h) * 128 * 2048;
    float*        Cb = ctxp + (long)kh * 8388608
                            + ((long)b * 2048 + q0) * 1024 + h * 128;

    // Q fragments resident (32 VGPR)
    bf16x8 qf[2][4];
#pragma unroll
    for (int qj = 0; qj < 2; ++qj)
#pragma unroll
        for (int kk = 0; kk < 4; ++kk)
            qf[qj][kk] = *(const bf16x8*)&Qb[(long)(qj * 16 + v) * 1024 + kk * 32 + u * 8];

    f32x4 ctxa[8][2];
#pragma unroll
    for (int dt = 0; dt < 8; ++dt)
#pragma unroll
        for (int qj = 0; qj < 2; ++qj) ctxa[dt][qj] = (f32x4){0.f, 0.f, 0.f, 0.f};

    char* PlwBase = (char*)&Pl[w][0][0];
    const char* Pl0 = (const char*)&Pl[0][0][0];
    const int swz = v & 7;

    // merged-reduce slot offsets for this wave's two groups (g = w, w+8)
    const int off_g0 = ((w & 1) * 16 + v) * 256
                     + ((((w >> 1) * 2 + (u >> 1)) ^ swz) * 16) + (u & 1) * 8;
    const int off_g1 = ((w & 1) * 16 + v) * 256
                     + (((((w >> 1) + 4) * 2 + (u >> 1)) ^ swz) * 16) + (u & 1) * 8;

    const int ktbase = kh * 1024;
    for (int it = 0; it < 8; ++it) {
        const int kt = ktbase + it * 128;

        // ---- step 0: batch-issue ALL kf loads (128 VGPR in flight) ----
        bf16x8 kf[8][4];
#pragma unroll
        for (int ki = 0; ki < 8; ++ki)
#pragma unroll
            for (int kk = 0; kk < 4; ++kk)
                kf[ki][kk] = *(const bf16x8*)&Kb[(long)(kt + ki * 16 + v) * 1024
                                                 + kk * 32 + u * 8];

        // ---- step 1: QK per ki (in-order consume), exp, pack into Pl ----
#pragma unroll
        for (int ki = 0; ki < 8; ++ki) {
            f32x4 e0 = (f32x4){0.f, 0.f, 0.f, 0.f};
            f32x4 e1 = (f32x4){0.f, 0.f, 0.f, 0.f};
#pragma unroll
            for (int kk = 0; kk < 4; ++kk) {
                e0 = mfma16(kf[ki][kk], qf[0][kk], e0);
                e1 = mfma16(kf[ki][kk], qf[1][kk], e1);
            }
#pragma unroll
            for (int r = 0; r < 4; ++r) { e0[r] = fexp(e0[r]); e1[r] = fexp(e1[r]); }
            const int choff = (((ki * 2 + (u >> 1)) ^ swz) * 16) + (u & 1) * 8;
            u32x2 w0; w0.x = pk2(e0[0], e0[1]); w0.y = pk2(e0[2], e0[3]);
            u32x2 w1; w1.x = pk2(e1[0], e1[1]); w1.y = pk2(e1[2], e1[3]);
            *(u32x2*)(PlwBase + v * 256 + choff) = w0;
            *(u32x2*)(PlwBase + (16 + v) * 256 + choff) = w1;
        }

        // ---- step V: batch-issue ALL vf loads (kf dead -> regs reused);
        //      in flight across both barriers + the reduce ----
        bf16x8 vf[8][4];
#pragma unroll
        for (int dt = 0; dt < 8; ++dt)
#pragma unroll
            for (int kc = 0; kc < 4; ++kc)
                vf[dt][kc] = *(const bf16x8*)&Vb[(long)(dt * 16 + v) * 2048
                                                 + kt + kc * 32 + u * 8];

        __syncthreads();

        // ---- step 2: merged reduce + normalize-writeback, groups {w, w+8} ----
#pragma unroll
        for (int gp = 0; gp < 2; ++gp) {
            const int off = gp ? off_g1 : off_g0;
            u32x2 dw[8];
#pragma unroll
            for (int wp = 0; wp < 8; ++wp)
                dw[wp] = *(const u32x2*)(Pl0 + wp * 8192 + off);
            f32x4 den = (f32x4){0.f, 0.f, 0.f, 0.f};
#pragma unroll
            for (int wp = 0; wp < 8; ++wp) {
                den[0] += bflo(dw[wp].x); den[1] += bfhi(dw[wp].x);
                den[2] += bflo(dw[wp].y); den[3] += bfhi(dw[wp].y);
            }
            f32x4 rv;
#pragma unroll
            for (int r = 0; r < 4; ++r) rv[r] = frcp(den[r]);
#pragma unroll
            for (int wp = 0; wp < 8; ++wp) {
                u32x2 nw;
                nw.x = pk2(bflo(dw[wp].x) * rv[0], bfhi(dw[wp].x) * rv[1]);
                nw.y = pk2(bflo(dw[wp].y) * rv[2], bfhi(dw[wp].y) * rv[3]);
                *(u32x2*)(const_cast<char*>(Pl0) + wp * 8192 + off) = nw;
            }
        }
        __syncthreads();

        // ---- step 3: PV from register-resident vf + Pl fragment reads ----
        __builtin_amdgcn_s_setprio(1);
#pragma unroll
        for (int kc = 0; kc < 4; ++kc) {
            bf16x8 pfr0 = *(const bf16x8*)(PlwBase + v * 256
                                           + (((kc * 4 + u) ^ swz) * 16));
            bf16x8 pfr1 = *(const bf16x8*)(PlwBase + (16 + v) * 256
                                           + (((kc * 4 + u) ^ swz) * 16));
#pragma unroll
            for (int dt = 0; dt < 8; ++dt) {
                ctxa[dt][0] = mfma16(vf[dt][kc], pfr0, ctxa[dt][0]);
                ctxa[dt][1] = mfma16(vf[dt][kc], pfr1, ctxa[dt][1]);
            }
        }
        __builtin_amdgcn_s_setprio(0);
    }

    // ---- epilogue: f32 partial, concat layout [b][q][h*128+dh] ----
#pragma unroll
    for (int dt = 0; dt < 8; ++dt)
#pragma unroll
        for (int qj = 0; qj < 2; ++qj)
            *(f32x4*)&Cb[(long)(qj * 16 + v) * 1024 + dt * 16 + u * 4] = ctxa[dt][qj];
}

// ---------------------------------------------------------------------------
// out[8192,1024] f32 = (A0+A1)[8192,1024]f32 * Bt[1024,1024]^T (bf16 weights)
// A-staging fuses the partial-sum add + bf16 cast. XCD row-panel remap.
__global__ __launch_bounds__(256, 2) void gemm_wo(
    const float* __restrict__ A0, const float* __restrict__ A1,
    const __bf16* __restrict__ Bt, float* __restrict__ out)
{
    __shared__ __bf16 As[128 * 32];
    __shared__ __bf16 Bs[128 * 32];
    const int tid  = threadIdx.x;
    const int lane = tid & 63;
    const int u = lane >> 4, v = lane & 15;
    const int w = tid >> 6;
    const int wm = (w >> 1) * 64, wn = (w & 1) * 64;
    const int bid = blockIdx.y * 8 + blockIdx.x;
    const long tM = (long)(bid & 63) * 128;
    const int  tN = (bid >> 6) * 128;

    f32x4 acc[4][4];
#pragma unroll
    for (int i = 0; i < 4; ++i)
#pragma unroll
        for (int j = 0; j < 4; ++j) acc[i][j] = (f32x4){0.f, 0.f, 0.f, 0.f};

    const int ar0 = tid >> 2, ak0 = (tid & 3) * 8;
    const int ar1 = ar0 + 64;

    const float*  a0 = A0 + tM * 1024;
    const float*  a1 = A1 + tM * 1024;
    const __bf16* Bb = Bt + (long)tN * 1024;

    for (int k0 = 0; k0 < 1024; k0 += 32) {
        __syncthreads();
        {
            const float* p0 = a0 + (long)ar0 * 1024 + k0 + ak0;
            const float* p1 = a1 + (long)ar0 * 1024 + k0 + ak0;
            float4 x0 = *(const float4*)p0, x1 = *(const float4*)(p0 + 4);
            float4 y0 = *(const float4*)p1, y1 = *(const float4*)(p1 + 4);
            bf16x8 o;
            o[0] = (__bf16)(x0.x + y0.x); o[1] = (__bf16)(x0.y + y0.y);
            o[2] = (__bf16)(x0.z + y0.z); o[3] = (__bf16)(x0.w + y0.w);
            o[4] = (__bf16)(x1.x + y1.x); o[5] = (__bf16)(x1.y + y1.y);
            o[6] = (__bf16)(x1.z + y1.z); o[7] = (__bf16)(x1.w + y1.w);
            *(bf16x8*)&As[ar0 * 32 + ak0] = o;
            const float* q0p = a0 + (long)ar1 * 1024 + k0 + ak0;
            const float* q1p = a1 + (long)ar1 * 1024 + k0 + ak0;
            float4 z0 = *(const float4*)q0p, z1 = *(const float4*)(q0p + 4);
            float4 t0 = *(const float4*)q1p, t1 = *(const float4*)(q1p + 4);
            bf16x8 o2;
            o2[0] = (__bf16)(z0.x + t0.x); o2[1] = (__bf16)(z0.y + t0.y);
            o2[2] = (__bf16)(z0.z + t0.z); o2[3] = (__bf16)(z0.w + t0.w);
            o2[4] = (__bf16)(z1.x + t1.x); o2[5] = (__bf16)(z1.y + t1.y);
            o2[6] = (__bf16)(z1.z + t1.z); o2[7] = (__bf16)(z1.w + t1.w);
            *(bf16x8*)&As[ar1 * 32 + ak0] = o2;
        }
        cp16(&Bs[ar0 * 32 + ak0], Bb + (long)ar0 * 1024 + k0 + ak0);
        cp16(&Bs[ar1 * 32 + ak0], Bb + (long)ar1 * 1024 + k0 + ak0);
        __syncthreads();

        bf16x8 af[4], bfr[4];
#pragma unroll
        for (int i = 0; i < 4; ++i)
            af[i] = *(const bf16x8*)&As[(wm + i * 16 + v) * 32 + u * 8];
#pragma unroll
        for (int j = 0; j < 4; ++j)
            bfr[j] = *(const bf16x8*)&Bs[(wn + j * 16 + v) * 32 + u * 8];
#pragma unroll
        for (int i = 0; i < 4; ++i)
#pragma unroll
            for (int j = 0; j < 4; ++j)
                acc[i][j] = mfma16(af[i], bfr[j], acc[i][j]);
    }

#pragma unroll
    for (int i = 0; i < 4; ++i) {
#pragma unroll
        for (int j = 0; j < 4; ++j) {
            const long row0 = tM + wm + i * 16 + u * 4;
            const int  col  = tN + wn + j * 16 + v;
#pragma unroll
            for (int r = 0; r < 4; ++r)
                out[(row0 + r) * 1024 + col] = acc[i][j][r];
        }
    }
}

// ---------------------------------------------------------------------------
extern "C" void kernel_launch(void* const* d_in, const int* in_sizes, int n_in,
                              void* d_out, int out_size, void* d_ws, size_t ws_size,
                              hipStream_t stream)
{
    const float* Q  = (const float*)d_in[0];
    const float* K  = (const float*)d_in[1];
    const float* V  = (const float*)d_in[2];
    const float* WQ = (const float*)d_in[3];
    const float* WK = (const float*)d_in[4];
    const float* WV = (const float*)d_in[5];
    const float* WO = (const float*)d_in[6];

    // workspace (bytes): 4x2MB weights + 3x16.8MB bf16 (qp,kp,vt)
    //                    + 2x33.6MB f32 ctx partials = 125.8 MB
    __bf16* ws = (__bf16*)d_ws;
    __bf16* wq = ws;
    __bf16* wk = wq + 1048576;
    __bf16* wv = wk + 1048576;
    __bf16* wo = wv + 1048576;
    __bf16* qp = wo + 1048576;
    __bf16* kp = qp + 8388608;
    __bf16* vt = kp + 8388608;
    float* ctxf = (float*)(vt + 8388608);    // 2 x 8388608 f32

    const float qscale = 0.08838834764831845f;   // 1/sqrt(128)

    cast4_f32_to_bf16<<<dim3(256, 4), 256, 0, stream>>>(
        WQ, wq, WK, wk, WV, wv, WO, wo, 262144);

    qkv_proj<<<dim3(8, 64, 3), 256, 0, stream>>>(
        Q, K, V, wq, wk, wv, qp, kp, vt, qscale);

    fused_attn<<<512, 512, 0, stream>>>(qp, kp, vt, ctxf);

    gemm_wo<<<dim3(8, 64), 256, 0, stream>>>(
        ctxf, ctxf + 8388608, wo, (float*)d_out);
}

// Round 8
// 487.955 us; speedup vs baseline: 1.1594x; 1.1594x over previous
//
#include <hip/hip_runtime.h>
#include <math.h>
#include <stdint.h>

// ---------------------------------------------------------------------------
// MultiHeadAttention, softmax over HEAD axis (dim=1), bf16 MFMA pipeline.
// B=4, S=2048, DIM=1024, H=8, DH=128.
//   Round-8 consolidation: measured-best components reassembled.
//   cast3/cast4 (bf16 casts, 25/5 us) -> qkv_proj (async cp16 A+B, 85 us,
//   + XCD row-panel remap) -> fused_attn v11 (v9 internals, 256 blocks,
//   16 iters, bf16 ctx direct) -> gemm_bt<1> (28 us).
//   fused_attn v11: per iter {QK 8x(8 MFMA) with 2-deep named-buffer ki
//   prefetch; fast exp; pack bf16(e) into own Pl slice; batch kc0 V-hoist;
//   bar; merged reduce+normalize-writeback (groups {w,w+8}); bar; PV with
//   kc-batched V loads}. LDS 64 KB Pl only. (512,2) cap - no spill.
// ---------------------------------------------------------------------------

typedef __attribute__((ext_vector_type(8))) __bf16 bf16x8;
typedef __attribute__((ext_vector_type(4))) __bf16 bf16x4;
typedef __attribute__((ext_vector_type(4))) float  f32x4;
typedef __attribute__((ext_vector_type(2))) unsigned int u32x2;

__device__ __forceinline__ f32x4 mfma16(bf16x8 a, bf16x8 b, f32x4 c) {
    return __builtin_amdgcn_mfma_f32_16x16x32_bf16(a, b, c, 0, 0, 0);
}

// async global->LDS, 16B per lane; LDS dest must be wave-uniform-base + lane*16
__device__ __forceinline__ void cp16(void* lds, const void* g) {
    __builtin_amdgcn_global_load_lds(
        (__attribute__((address_space(1))) void*)(void*)(const_cast<void*>(g)),
        (__attribute__((address_space(3))) void*)lds,
        16, 0, 0);
}

// fast exp/rcp: single HW transcendental.
__device__ __forceinline__ float fexp(float x) {
    float r;
    asm("v_exp_f32 %0, %1" : "=v"(r) : "v"(x * 1.44269504088896341f));
    return r;
}
__device__ __forceinline__ float frcp(float x) {
    float r;
    asm("v_rcp_f32 %0, %1" : "=v"(r) : "v"(x));
    return r;
}

// pack two f32 into a dword of two bf16 (RNE via HW cvt)
__device__ __forceinline__ uint32_t pk2(float a, float b) {
    __bf16 x = (__bf16)a, y = (__bf16)b;
    unsigned short xa = __builtin_bit_cast(unsigned short, x);
    unsigned short yb = __builtin_bit_cast(unsigned short, y);
    return (uint32_t)xa | ((uint32_t)yb << 16);
}
__device__ __forceinline__ float bflo(uint32_t d) {
    return __builtin_bit_cast(float, d << 16);
}
__device__ __forceinline__ float bfhi(uint32_t d) {
    return __builtin_bit_cast(float, d & 0xffff0000u);
}

// ---------------------------------------------------------------------------
// 4 weight tensors in one launch
__global__ void cast4_f32_to_bf16(const float* __restrict__ s0, __bf16* __restrict__ d0,
                                  const float* __restrict__ s1, __bf16* __restrict__ d1,
                                  const float* __restrict__ s2, __bf16* __restrict__ d2,
                                  const float* __restrict__ s3, __bf16* __restrict__ d3,
                                  int n4) {
    const float* s = (blockIdx.y == 0) ? s0 : (blockIdx.y == 1) ? s1
                    : (blockIdx.y == 2) ? s2 : s3;
    __bf16* d = (blockIdx.y == 0) ? d0 : (blockIdx.y == 1) ? d1
               : (blockIdx.y == 2) ? d2 : d3;
    int i = blockIdx.x * blockDim.x + threadIdx.x;
    const int stride = gridDim.x * blockDim.x;
    for (; i < n4; i += stride) {
        float4 f = ((const float4*)s)[i];
        bf16x4 o;
        o[0] = (__bf16)f.x; o[1] = (__bf16)f.y; o[2] = (__bf16)f.z; o[3] = (__bf16)f.w;
        ((bf16x4*)d)[i] = o;
    }
}

// Q, K, V activations in one launch (y selects tensor)
__global__ void cast3_f32_to_bf16(const float* __restrict__ s0, __bf16* __restrict__ d0,
                                  const float* __restrict__ s1, __bf16* __restrict__ d1,
                                  const float* __restrict__ s2, __bf16* __restrict__ d2,
                                  int n4) {
    const float* s = (blockIdx.y == 0) ? s0 : (blockIdx.y == 1) ? s1 : s2;
    __bf16* d = (blockIdx.y == 0) ? d0 : (blockIdx.y == 1) ? d1 : d2;
    int i = blockIdx.x * blockDim.x + threadIdx.x;
    const int stride = gridDim.x * blockDim.x;
    for (; i < n4; i += stride) {
        float4 f = ((const float4*)s)[i];
        bf16x4 o;
        o[0] = (__bf16)f.x; o[1] = (__bf16)f.y; o[2] = (__bf16)f.z; o[3] = (__bf16)f.w;
        ((bf16x4*)d)[i] = o;
    }
}

// ---------------------------------------------------------------------------
// C[8192,1024] = A[8192,1024] * Bt[1024,1024]^T   (Bt stored [N,K] row-major)
// MODE 1: f32 out (final WO projection). XCD row-panel remap.
template<int MODE>
__global__ __launch_bounds__(256, 2) void gemm_bt(const __bf16* __restrict__ A,
                                                  const __bf16* __restrict__ Bt,
                                                  void* __restrict__ out,
                                                  float scale)
{
    __shared__ __bf16 As[128 * 32];
    __shared__ __bf16 Bs[128 * 32];
    const int tid  = threadIdx.x;
    const int lane = tid & 63;
    const int u = lane >> 4, v = lane & 15;
    const int w = tid >> 6;
    const int wm = (w >> 1) * 64, wn = (w & 1) * 64;
    const int bid = blockIdx.y * 8 + blockIdx.x;
    const long tM = (long)(bid & 63) * 128;
    const int  tN = (bid >> 6) * 128;

    f32x4 acc[4][4];
#pragma unroll
    for (int i = 0; i < 4; ++i)
#pragma unroll
        for (int j = 0; j < 4; ++j) acc[i][j] = (f32x4){0.f, 0.f, 0.f, 0.f};

    const int c0 = tid, c1 = tid + 256;
    const int ar0 = c0 >> 2, ak0 = (c0 & 3) * 8;
    const int ar1 = c1 >> 2, ak1 = (c1 & 3) * 8;

    const __bf16* Ab = A  + tM * 1024;
    const __bf16* Bb = Bt + (long)tN * 1024;

    for (int k0 = 0; k0 < 1024; k0 += 32) {
        __syncthreads();
        cp16(&As[ar0 * 32 + ak0], Ab + (long)ar0 * 1024 + k0 + ak0);
        cp16(&As[ar1 * 32 + ak1], Ab + (long)ar1 * 1024 + k0 + ak1);
        cp16(&Bs[ar0 * 32 + ak0], Bb + (long)ar0 * 1024 + k0 + ak0);
        cp16(&Bs[ar1 * 32 + ak1], Bb + (long)ar1 * 1024 + k0 + ak1);
        __syncthreads();

        bf16x8 af[4], bfr[4];
#pragma unroll
        for (int i = 0; i < 4; ++i)
            af[i] = *(const bf16x8*)&As[(wm + i * 16 + v) * 32 + u * 8];
#pragma unroll
        for (int j = 0; j < 4; ++j)
            bfr[j] = *(const bf16x8*)&Bs[(wn + j * 16 + v) * 32 + u * 8];
#pragma unroll
        for (int i = 0; i < 4; ++i)
#pragma unroll
            for (int j = 0; j < 4; ++j)
                acc[i][j] = mfma16(af[i], bfr[j], acc[i][j]);
    }

#pragma unroll
    for (int i = 0; i < 4; ++i) {
#pragma unroll
        for (int j = 0; j < 4; ++j) {
            const long row0 = tM + wm + i * 16 + u * 4;
            const int  col  = tN + wn + j * 16 + v;
            if (MODE == 1) {
                float* o = (float*)out;
#pragma unroll
                for (int r = 0; r < 4; ++r)
                    o[(row0 + r) * 1024 + col] = acc[i][j][r];
            } else {
                __bf16* o = (__bf16*)out;
#pragma unroll
                for (int r = 0; r < 4; ++r)
                    o[(row0 + r) * 1024 + col] = (__bf16)(acc[i][j][r] * scale);
            }
        }
    }
}

// ---------------------------------------------------------------------------
// Batched Q/K/V projection, bf16 inputs, async cp16 for BOTH operands
// (round-2's measured 85us version) + XCD row-panel remap.
// z=0: qp=(Xq WQ^T)*qscale; z=1: kp=Xk WK^T; z=2: vt=(Xv WV^T)^T [b,h,dh,s]
__global__ __launch_bounds__(256, 2) void qkv_proj(
    const __bf16* __restrict__ xq, const __bf16* __restrict__ xk,
    const __bf16* __restrict__ xv,
    const __bf16* __restrict__ wq, const __bf16* __restrict__ wk,
    const __bf16* __restrict__ wv,
    __bf16* __restrict__ qp, __bf16* __restrict__ kp, __bf16* __restrict__ vtb,
    float qscale)
{
    __shared__ __bf16 As[128 * 32];
    __shared__ __bf16 Bs[128 * 32];
    const int z = blockIdx.z;
    const __bf16* A  = (z == 0) ? xq : (z == 1) ? xk : xv;
    const __bf16* Bt = (z == 0) ? wq : (z == 1) ? wk : wv;
    __bf16* out      = (z == 0) ? qp : (z == 1) ? kp : vtb;
    const float scale = (z == 0) ? qscale : 1.0f;

    const int tid  = threadIdx.x;
    const int lane = tid & 63;
    const int u = lane >> 4, v = lane & 15;
    const int w = tid >> 6;
    const int wm = (w >> 1) * 64, wn = (w & 1) * 64;
    const int bid = blockIdx.y * 8 + blockIdx.x;
    const long tM = (long)(bid & 63) * 128;
    const int  tN = (bid >> 6) * 128;

    f32x4 acc[4][4];
#pragma unroll
    for (int i = 0; i < 4; ++i)
#pragma unroll
        for (int j = 0; j < 4; ++j) acc[i][j] = (f32x4){0.f, 0.f, 0.f, 0.f};

    const int c0 = tid, c1 = tid + 256;
    const int ar0 = c0 >> 2, ak0 = (c0 & 3) * 8;
    const int ar1 = c1 >> 2, ak1 = (c1 & 3) * 8;

    const __bf16* Ab = A  + tM * 1024;
    const __bf16* Bb = Bt + (long)tN * 1024;

    for (int k0 = 0; k0 < 1024; k0 += 32) {
        __syncthreads();
        cp16(&As[ar0 * 32 + ak0], Ab + (long)ar0 * 1024 + k0 + ak0);
        cp16(&As[ar1 * 32 + ak1], Ab + (long)ar1 * 1024 + k0 + ak1);
        cp16(&Bs[ar0 * 32 + ak0], Bb + (long)ar0 * 1024 + k0 + ak0);
        cp16(&Bs[ar1 * 32 + ak1], Bb + (long)ar1 * 1024 + k0 + ak1);
        __syncthreads();

        bf16x8 af[4], bfr[4];
#pragma unroll
        for (int i = 0; i < 4; ++i)
            af[i] = *(const bf16x8*)&As[(wm + i * 16 + v) * 32 + u * 8];
#pragma unroll
        for (int j = 0; j < 4; ++j)
            bfr[j] = *(const bf16x8*)&Bs[(wn + j * 16 + v) * 32 + u * 8];
#pragma unroll
        for (int i = 0; i < 4; ++i)
#pragma unroll
            for (int j = 0; j < 4; ++j)
                acc[i][j] = mfma16(af[i], bfr[j], acc[i][j]);
    }

#pragma unroll
    for (int i = 0; i < 4; ++i) {
#pragma unroll
        for (int j = 0; j < 4; ++j) {
            const long row0 = tM + wm + i * 16 + u * 4;
            const int  col  = tN + wn + j * 16 + v;
            if (z < 2) {
#pragma unroll
                for (int r = 0; r < 4; ++r)
                    out[(row0 + r) * 1024 + col] = (__bf16)(acc[i][j][r] * scale);
            } else {
                const int bidx = (int)(row0 >> 11);
                const int s    = (int)(row0 & 2047);          // 4-aligned
                const int h = col >> 7, dh = col & 127;
                bf16x4 pkv;
#pragma unroll
                for (int r = 0; r < 4; ++r) pkv[r] = (__bf16)acc[i][j][r];
                *(bf16x4*)&out[((long)(bidx * 8 + h) * 128 + dh) * 2048 + s] = pkv;
            }
        }
    }
}

// ---------------------------------------------------------------------------
// fused_attn v11: QK^T -> head-softmax -> PV.
// 256 blocks (v6's measured grid: XCD bid&7 clusters a batch on 2 XCDs),
// 512 threads = 8 waves, wave w == head. q-tile 32, KT=128, 16 iters.
//
// Pl element (k = ki*16 + kk8*8 + kk4*4 + r, q = qj*16 + vq) of wave slice w
// lives at byte: w*8192 + (qj*16+vq)*256 + ((ki*2+kk8)^(vq&7))*16 + kk4*8 + r*2.
//   step1: ki-pairs with 2-deep NAMED-buffer prefetch (kfA/kfB, static
//          parity -> no dynamic indexing, no spill): load ki+1 while
//          computing ki. 8 QK MFMA + fexp + pack per ki.
//   vhoist: kc=0 V group (8 b128) issued pre-barrier, consumed in PV.
//   bar; step2: wave w merged-reduces groups {w,w+8} across all 8 slices
//          and writes back NORMALIZED values; bar.
//   step3: PV per kc: batch 8 V loads + 2 Pl fragment reads + 16 MFMA.
// LDS: Pl 64 KB. (512,2): proven no-spill envelope. ctx bf16 direct out.
__global__ __launch_bounds__(512, 2) void fused_attn(
    const __bf16* __restrict__ qp, const __bf16* __restrict__ kp,
    const __bf16* __restrict__ vt, __bf16* __restrict__ ctx)
{
    __shared__ __bf16 Pl[8][32][128];   // 64 KB; per-wave slice 8 KB

    const int tid  = threadIdx.x;
    const int w    = tid >> 6;          // wave == head
    const int lane = tid & 63;
    const int u = lane >> 4, v = lane & 15;

    // v6 mapping: XCD (bid&7) serves one batch b; qt spread across XCDs
    const int g0 = blockIdx.x;
    const int xs = g0 & 7, idx = g0 >> 3;
    const int b  = xs >> 1;
    const int qt = idx * 2 + (xs & 1);
    const int q0 = qt * 32;
    const int h  = w;

    const __bf16* Qb = qp + ((long)b * 2048 + q0) * 1024 + h * 128;
    const __bf16* Kb = kp + (long)b * 2048 * 1024 + h * 128;
    const __bf16* Vb = vt + (long)(b * 8 + h) * 128 * 2048;

    // Q fragments resident (32 VGPR)
    bf16x8 qf[2][4];
#pragma unroll
    for (int qj = 0; qj < 2; ++qj)
#pragma unroll
        for (int kk = 0; kk < 4; ++kk)
            qf[qj][kk] = *(const bf16x8*)&Qb[(long)(qj * 16 + v) * 1024 + kk * 32 + u * 8];

    f32x4 ctxa[8][2];
#pragma unroll
    for (int dt = 0; dt < 8; ++dt)
#pragma unroll
        for (int qj = 0; qj < 2; ++qj) ctxa[dt][qj] = (f32x4){0.f, 0.f, 0.f, 0.f};

    char* PlwBase = (char*)&Pl[w][0][0];
    const char* Pl0 = (const char*)&Pl[0][0][0];
    const int swz = v & 7;

    // merged-reduce slot offsets for this wave's two groups (g = w, w+8)
    const int off_g0 = ((w & 1) * 16 + v) * 256
                     + ((((w >> 1) * 2 + (u >> 1)) ^ swz) * 16) + (u & 1) * 8;
    const int off_g1 = ((w & 1) * 16 + v) * 256
                     + (((((w >> 1) + 4) * 2 + (u >> 1)) ^ swz) * 16) + (u & 1) * 8;

    for (int it = 0; it < 16; ++it) {
        const int kt = it * 128;

        // ---- step 1: QK with 2-deep named-buffer ki prefetch ----
        bf16x8 kfA[4], kfB[4];
#pragma unroll
        for (int kk = 0; kk < 4; ++kk)
            kfA[kk] = *(const bf16x8*)&Kb[(long)(kt + v) * 1024 + kk * 32 + u * 8];

#pragma unroll
        for (int kp2 = 0; kp2 < 4; ++kp2) {
            const int ki0 = kp2 * 2, ki1 = kp2 * 2 + 1;
            // prefetch group ki1 into kfB while computing ki0 from kfA
#pragma unroll
            for (int kk = 0; kk < 4; ++kk)
                kfB[kk] = *(const bf16x8*)&Kb[(long)(kt + ki1 * 16 + v) * 1024
                                              + kk * 32 + u * 8];
            {
                f32x4 e0 = (f32x4){0.f, 0.f, 0.f, 0.f};
                f32x4 e1 = (f32x4){0.f, 0.f, 0.f, 0.f};
#pragma unroll
                for (int kk = 0; kk < 4; ++kk) {
                    e0 = mfma16(kfA[kk], qf[0][kk], e0);
                    e1 = mfma16(kfA[kk], qf[1][kk], e1);
                }
#pragma unroll
                for (int r = 0; r < 4; ++r) { e0[r] = fexp(e0[r]); e1[r] = fexp(e1[r]); }
                const int choff = (((ki0 * 2 + (u >> 1)) ^ swz) * 16) + (u & 1) * 8;
                u32x2 w0; w0.x = pk2(e0[0], e0[1]); w0.y = pk2(e0[2], e0[3]);
                u32x2 w1; w1.x = pk2(e1[0], e1[1]); w1.y = pk2(e1[2], e1[3]);
                *(u32x2*)(PlwBase + v * 256 + choff) = w0;
                *(u32x2*)(PlwBase + (16 + v) * 256 + choff) = w1;
            }
            // prefetch group ki1+1 into kfA (except last) while computing ki1
            if (ki1 < 7) {
#pragma unroll
                for (int kk = 0; kk < 4; ++kk)
                    kfA[kk] = *(const bf16x8*)&Kb[(long)(kt + (ki1 + 1) * 16 + v) * 1024
                                                  + kk * 32 + u * 8];
            }
            {
                f32x4 e0 = (f32x4){0.f, 0.f, 0.f, 0.f};
                f32x4 e1 = (f32x4){0.f, 0.f, 0.f, 0.f};
#pragma unroll
                for (int kk = 0; kk < 4; ++kk) {
                    e0 = mfma16(kfB[kk], qf[0][kk], e0);
                    e1 = mfma16(kfB[kk], qf[1][kk], e1);
                }
#pragma unroll
                for (int r = 0; r < 4; ++r) { e0[r] = fexp(e0[r]); e1[r] = fexp(e1[r]); }
                const int choff = (((ki1 * 2 + (u >> 1)) ^ swz) * 16) + (u & 1) * 8;
                u32x2 w0; w0.x = pk2(e0[0], e0[1]); w0.y = pk2(e0[2], e0[3]);
                u32x2 w1; w1.x = pk2(e1[0], e1[1]); w1.y = pk2(e1[2], e1[3]);
                *(u32x2*)(PlwBase + v * 256 + choff) = w0;
                *(u32x2*)(PlwBase + (16 + v) * 256 + choff) = w1;
            }
        }

        // hoist PV kc=0 V group across the barriers (32 VGPR in flight)
        bf16x8 vhoist[8];
#pragma unroll
        for (int dt = 0; dt < 8; ++dt)
            vhoist[dt] = *(const bf16x8*)&Vb[(long)(dt * 16 + v) * 2048 + kt + u * 8];

        __syncthreads();

        // ---- step 2: merged reduce + normalize-writeback, groups {w, w+8} ----
#pragma unroll
        for (int gp = 0; gp < 2; ++gp) {
            const int off = gp ? off_g1 : off_g0;
            u32x2 dw[8];
#pragma unroll
            for (int wp = 0; wp < 8; ++wp)
                dw[wp] = *(const u32x2*)(Pl0 + wp * 8192 + off);
            f32x4 den = (f32x4){0.f, 0.f, 0.f, 0.f};
#pragma unroll
            for (int wp = 0; wp < 8; ++wp) {
                den[0] += bflo(dw[wp].x); den[1] += bfhi(dw[wp].x);
                den[2] += bflo(dw[wp].y); den[3] += bfhi(dw[wp].y);
            }
            f32x4 rv;
#pragma unroll
            for (int r = 0; r < 4; ++r) rv[r] = frcp(den[r]);
#pragma unroll
            for (int wp = 0; wp < 8; ++wp) {
                u32x2 nw;
                nw.x = pk2(bflo(dw[wp].x) * rv[0], bfhi(dw[wp].x) * rv[1]);
                nw.y = pk2(bflo(dw[wp].y) * rv[2], bfhi(dw[wp].y) * rv[3]);
                *(u32x2*)(const_cast<char*>(Pl0) + wp * 8192 + off) = nw;
            }
        }
        __syncthreads();

        // ---- step 3: PV per kc: batched V group + Pl fragment reads ----
        __builtin_amdgcn_s_setprio(1);
#pragma unroll
        for (int kc = 0; kc < 4; ++kc) {
            bf16x8 vg[8];
#pragma unroll
            for (int dt = 0; dt < 8; ++dt)
                vg[dt] = (kc == 0) ? vhoist[dt]
                       : *(const bf16x8*)&Vb[(long)(dt * 16 + v) * 2048
                                             + kt + kc * 32 + u * 8];
            bf16x8 pfr0 = *(const bf16x8*)(PlwBase + v * 256
                                           + (((kc * 4 + u) ^ swz) * 16));
            bf16x8 pfr1 = *(const bf16x8*)(PlwBase + (16 + v) * 256
                                           + (((kc * 4 + u) ^ swz) * 16));
#pragma unroll
            for (int dt = 0; dt < 8; ++dt) {
                ctxa[dt][0] = mfma16(vg[dt], pfr0, ctxa[dt][0]);
                ctxa[dt][1] = mfma16(vg[dt], pfr1, ctxa[dt][1]);
            }
        }
        __builtin_amdgcn_s_setprio(0);
    }

    // ---- epilogue: bf16 ctx, concat layout [b][q][h*128+dh] ----
#pragma unroll
    for (int dt = 0; dt < 8; ++dt)
#pragma unroll
        for (int qj = 0; qj < 2; ++qj) {
            bf16x4 o;
#pragma unroll
            for (int r = 0; r < 4; ++r) o[r] = (__bf16)ctxa[dt][qj][r];
            *(bf16x4*)&ctx[((long)b * 2048 + q0 + qj * 16 + v) * 1024
                           + h * 128 + dt * 16 + u * 4] = o;
        }
}

// ---------------------------------------------------------------------------
extern "C" void kernel_launch(void* const* d_in, const int* in_sizes, int n_in,
                              void* d_out, int out_size, void* d_ws, size_t ws_size,
                              hipStream_t stream)
{
    const float* Q  = (const float*)d_in[0];
    const float* K  = (const float*)d_in[1];
    const float* V  = (const float*)d_in[2];
    const float* WQ = (const float*)d_in[3];
    const float* WK = (const float*)d_in[4];
    const float* WV = (const float*)d_in[5];
    const float* WO = (const float*)d_in[6];

    // workspace (bf16 elems): 4x 1M weights + 7x 8.4M tensors = 125.8 MB
    __bf16* ws = (__bf16*)d_ws;
    __bf16* wq = ws;
    __bf16* wk = wq + 1048576;
    __bf16* wv = wk + 1048576;
    __bf16* wo = wv + 1048576;
    __bf16* xq = wo + 1048576;     // Q cast
    __bf16* xk = xq + 8388608;     // K cast
    __bf16* xv = xk + 8388608;     // V cast
    __bf16* qp = xv + 8388608;
    __bf16* kp = qp + 8388608;
    __bf16* vt = kp + 8388608;
    __bf16* xb = vt + 8388608;     // ctx (bf16)

    const float qscale = 0.08838834764831845f;   // 1/sqrt(128)

    cast4_f32_to_bf16<<<dim3(256, 4), 256, 0, stream>>>(
        WQ, wq, WK, wk, WV, wv, WO, wo, 262144);
    cast3_f32_to_bf16<<<dim3(2048, 3), 256, 0, stream>>>(
        Q, xq, K, xk, V, xv, 2097152);
    qkv_proj<<<dim3(8, 64, 3), 256, 0, stream>>>(
        xq, xk, xv, wq, wk, wv, qp, kp, vt, qscale);

    fused_attn<<<256, 512, 0, stream>>>(qp, kp, vt, xb);

    gemm_bt<1><<<dim3(8, 64), 256, 0, stream>>>(xb, wo, (float*)d_out, 1.0f);
}